// Round 10
// baseline (65.266 us; speedup 1.0000x reference)
//
#include <hip/hip_runtime.h>
#include <stdint.h>

// Detection post-processor, two kernels (best-measured structure, R6 base):
//  K1: coalesced score scan -> per-class candidate key lists (ws)
//  K2: per-class rank-sort (overlapped head loads) + adjacency-mask greedy
//      NMS + packed emission; last-finishing block runs the global top-100.
// N=2048 proposals, C=81 classes (class 0 dropped).
// Inputs:  d_in[0] = boxes  [2048, 324] f32, d_in[1] = scores [2048, 81] f32
// Output:  d_out = [100, 6] f32 (x1,y1,x2,y2,score,label)
// Workspace (190784 B <= 192000; [0,5184) zeroed per call by memset node):
//   [0]      u32 gdone            NMS-done counter
//   [64]     u32 cnt[80*16]       padded per-class candidate counters
//   [5184]   u64 keyws[80*190]    per-class candidate keys
//   [126784] u64 psarr[8000]      per-(class,rank) packed (k32,cls,pi); 0 pad

#define NPROP   2048
#define NCLS    81
#define SCORE_T 0.05f
#define NMS_T   0.5f
#define PERCLS  100
#define NREC    (80 * PERCLS)   // 8000
#define NEGINF  -1.0e9f
#define NBIN    4096
#define SELCAP  4096
#define MCAP    190             // fast-path candidate cap per class

typedef unsigned long long u64;
typedef unsigned int u32;

__device__ __forceinline__ u32 fflip(float f) {
  u32 u = __float_as_uint(f);
  return (u & 0x80000000u) ? ~u : (u | 0x80000000u);
}
__device__ __forceinline__ float funflip(u32 u) {
  u32 v = (u & 0x80000000u) ? (u ^ 0x80000000u) : ~u;
  return __uint_as_float(v);
}
__device__ __forceinline__ float4 clip_box(float4 r) {
  float4 b;
  b.x = fminf(fmaxf(r.x, 0.f), 1332.f);
  b.y = fminf(fmaxf(r.y, 0.f), 799.f);
  b.z = fminf(fmaxf(r.z, 0.f), 1332.f);
  b.w = fminf(fmaxf(r.w, 0.f), 799.f);
  return b;
}
// Reference IoU (exact expression; symmetric and f32-commutative).
__device__ __forceinline__ float iou_ref(float4 a, float aarea, float4 b,
                                         float barea) {
  float ix1 = fmaxf(a.x, b.x), iy1 = fmaxf(a.y, b.y);
  float ix2 = fminf(a.z, b.z), iy2 = fminf(a.w, b.w);
  float inter = fmaxf(ix2 - ix1, 0.f) * fmaxf(iy2 - iy1, 0.f);
  return inter / (aarea + barea - inter + 1e-9f);
}

// Sort key: [63:32] fflip(score), [31:0] ~proposal_idx. Descending order ==
// (score desc, idx asc) == the reference's stable argsort(-s_masked). Unique.
// Packed record: [63:32] fflip(score), [17:11] 79-cls, [10:0] 2047-pi.
// Descending order == (score desc, cls asc, pi asc) == lax.top_k tie order
// (lowest flat index first). Validated in R8/R9 (absmax 0).

// ---- Kernel 1: coalesced scan. 162 blocks x 256 thr, 1 float4/thread. ----
__global__ __launch_bounds__(256) void scan_kernel(
    const float4* __restrict__ scores4, u32* __restrict__ cnt,
    u64* __restrict__ keyws) {
  const int g = blockIdx.x * 256 + threadIdx.x;   // 41472 = 2048*81/4 exactly
  const float4 s4 = scores4[g];
  const int flat = g * 4;
  #pragma unroll
  for (int t = 0; t < 4; ++t) {
    float s = (t == 0) ? s4.x : (t == 1) ? s4.y : (t == 2) ? s4.z : s4.w;
    int f = flat + t;
    int i = f / 81;
    int c = f - i * 81;
    if (c != 0 && s > SCORE_T) {
      int cls = c - 1;
      int slot = (int)atomicAdd(&cnt[cls * 16], 1u);
      if (slot < MCAP)
        keyws[cls * MCAP + slot] = ((u64)fflip(s) << 32) | (u32)(~(u32)i);
    }
  }
}

// ---- Kernel 2: per-class sort + mask-NMS; last block runs global top-100.
__global__ __launch_bounds__(256) void nms_topk_kernel(
    const float* __restrict__ boxes, const float* __restrict__ scores,
    const u32* __restrict__ cnt, const u64* __restrict__ keyws,
    u64* __restrict__ psarr, u32* __restrict__ gdone,
    float* __restrict__ out) {
  __shared__ __align__(16) char arena[50176];
  u64*    keysLds  = (u64*)arena;                   // [2048] 16384 B (slow path)
  u64*    sortedA  = (u64*)(arena + 16384);         // [190]   1520 B
  float4* bxR      = (float4*)(arena + 17920);      // [190]   3040 B rank-idx
  float4* keptBx   = (float4*)(arena + 20992);      // [100]   1600 B
  float*  keptArea = (float*)(arena + 22592);       // [100]    400 B
  float4* bxC      = (float4*)(arena + 23040);      // [64]    1024 B chunk stage
  // --- topk overlay (last block only, after NMS emission is done) ---
  u32*    hist     = (u32*)arena;                   // [4096] 16384 B
  u64*    sel      = (u64*)(arena + 16384);         // [4096] 32768 B
  u64*    selSorted= (u64*)(arena + 49152);         // [128]   1024 B

  __shared__ int mcount, kkOut, lastOld, selCount;
  __shared__ volatile int sC, sB;
  __shared__ volatile u32 sNeed;

  const int tid = threadIdx.x;
  const int c = blockIdx.x + 1;                     // class 1..80
  const int cls = c - 1;

  // Overlapped head loads: cnt, keys, and masked key-dependent box gather
  // all in flight together (one memory round, no serial chain).
  u64 kr = 0ULL;
  float4 raw = make_float4(0.f, 0.f, 0.f, 0.f);
  if (tid < MCAP) {
    kr = keyws[cls * MCAP + tid];
    u32 pi = (~(u32)kr) & (NPROP - 1);    // masked: safe even for stale slots
    raw = *(const float4*)(boxes + (size_t)pi * (NCLS * 4) + c * 4);
  }
  const int M0 = (int)cnt[cls * 16];
  const bool fast = (M0 <= MCAP);
  int M;

  if (fast) {
    M = M0;
    if (tid < M) keysLds[tid] = kr;
    __syncthreads();
    if (tid < M) {
      int rk = 0;
      for (int j = 0; j < M; ++j) rk += (keysLds[j] > kr) ? 1 : 0;
      sortedA[rk] = kr;
      bxR[rk] = clip_box(raw);            // direct place at own rank
    }
    __syncthreads();
  } else {
    // Slow fallback (correctness only; keyws contents ignored):
    // strided rescan + block bitonic sort.
    if (tid == 0) mcount = 0;
    __syncthreads();
    for (int i = tid; i < NPROP; i += 256) {
      float s = scores[i * NCLS + c];
      if (s > SCORE_T) {
        int slot = atomicAdd(&mcount, 1);
        keysLds[slot] = ((u64)fflip(s) << 32) | (u32)(~(u32)i);
      }
    }
    __syncthreads();
    M = mcount;
    int P = 256; while (P < M) P <<= 1;
    for (int i = M + tid; i < P; i += 256) keysLds[i] = 0ULL;
    __syncthreads();
    for (int k = 2; k <= P; k <<= 1) {
      for (int j = k >> 1; j > 0; j >>= 1) {
        for (int i = tid; i < P; i += 256) {
          int ixj = i ^ j;
          if (ixj > i) {
            u64 a = keysLds[i], b = keysLds[ixj];
            if (((i & k) == 0) ? (a < b) : (a > b)) { keysLds[i] = b; keysLds[ixj] = a; }
          }
        }
        __syncthreads();
      }
    }
  }
  const u64* SK = fast ? sortedA : keysLds;

  u64* pbase = psarr + cls * PERCLS;

  // ---- Greedy NMS, adjacency-mask form (wave 0 only). Semantics identical
  // to greedy: a candidate dies iff an earlier KEPT candidate has IoU>thresh.
  if (tid < 64) {
    const int lane = tid;
    int kkTot = 0;
    const int NC = (M + 63) >> 6;
    for (int q = 0; q < NC && kkTot < PERCLS; ++q) {
      const int cbase = q << 6;
      const int ccnt = min(64, M - cbase);
      u64 mykey = 0ULL;
      float4 b = make_float4(0.f, 0.f, 0.f, 0.f);
      int alive = 0;
      if (lane < ccnt) {
        mykey = SK[cbase + lane];
        if (fast) {
          b = bxR[cbase + lane];
        } else {
          u32 pi = ~(u32)mykey;
          b = clip_box(*(const float4*)(boxes + (size_t)pi * (NCLS * 4) + c * 4));
        }
        alive = 1;
      }
      bxC[lane] = b;                       // stage chunk boxes (wave-sync)
      const float barea = fmaxf(b.z - b.x, 0.f) * fmaxf(b.w - b.y, 0.f);
      __builtin_amdgcn_wave_barrier();

      // (0) cross-chunk: dead if any already-kept box overlaps me.
      for (int t = 0; t < kkTot; ++t) {
        float4 kb = keptBx[t];
        if (iou_ref(kb, keptArea[t], b, barea) > NMS_T) alive = 0;
      }

      // (a) intra-chunk suppression row: bits j > lane with IoU > thresh.
      u64 supRow = 0ULL;
      for (int j = 0; j < ccnt; ++j) {
        float4 ob = bxC[j];                // LDS broadcast
        float oarea = fmaxf(ob.z - ob.x, 0.f) * fmaxf(ob.w - ob.y, 0.f);
        bool hit = (j > lane) && (iou_ref(b, barea, ob, oarea) > NMS_T);
        supRow |= (u64)(hit ? 1u : 0u) << j;
      }
      const u32 rowLo = (u32)supRow, rowHi = (u32)(supRow >> 32);

      // (b) scalar propagation over alive candidates in rank order.
      u64 work = __ballot(alive != 0);
      u64 kept = 0ULL;
      while (work) {
        int i = (int)__builtin_ctzll(work);
        u32 rl = __builtin_amdgcn_readlane(rowLo, i);
        u32 rh = __builtin_amdgcn_readlane(rowHi, i);
        kept |= 1ull << i;
        work &= ~(((u64)rh << 32) | rl);
        work &= work - 1;                  // clear bit i
      }

      // cap at PERCLS kept per class (trim highest ranks; then we stop).
      int budget = PERCLS - kkTot;
      int over = (int)__popcll(kept) - budget;
      while (over-- > 0) kept &= ~(1ull << (63 - __builtin_clzll(kept)));

      // (c) parallel emission of packed records in rank order.
      if ((kept >> lane) & 1ull) {
        int rank = kkTot + (int)__popcll(kept & ((1ull << lane) - 1ull));
        u32 k32 = (u32)(mykey >> 32);
        // low 11 bits of mykey == 2047 - pi  (mykey[31:0] = ~pi, pi < 2048)
        pbase[rank] = ((u64)k32 << 32) | ((u64)(u32)(79 - cls) << 11) |
                      (u64)((u32)mykey & 0x7FFu);
        keptBx[rank] = b;
        keptArea[rank] = barea;
      }
      kkTot += (int)__popcll(kept);
      __builtin_amdgcn_wave_barrier();
    }
    if (lane == 0) kkOut = kkTot;
  }
  __syncthreads();

  // Pad remaining slots with 0 (skipped by the tail histogram; pads never
  // reach the top-100 for this workload).
  for (int slot = kkOut + tid; slot < PERCLS; slot += 256) pbase[slot] = 0ULL;

  // ---- Last block to finish runs the global top-100 ----
  __threadfence();          // release this block's psarr stores
  __syncthreads();
  if (tid == 0) lastOld = (int)atomicAdd(gdone, 1u);   // device-scope
  __syncthreads();
  if (lastOld != 79) return;
  __threadfence();          // acquire: see all other blocks' stores

  for (int b = tid; b < NBIN; b += 256) hist[b] = 0;
  if (tid == 0) { selCount = 0; sC = 0; sNeed = 1; sB = 0; }
  if (tid < 128) selSorted[tid] = 0ULL;
  __syncthreads();

  // Histogram over packed records. Bucket = bits [26:15] of fflip(score):
  // kept scores in (0.05,1] share fflip's top 5 bits (0b10111), so bucket
  // order == score order; zero pads fail the tag test and are skipped.
  for (int e = tid; e < NREC; e += 256) {
    u32 k32 = (u32)(psarr[e] >> 32);
    if ((k32 >> 27) == 0x17u) atomicAdd(&hist[(k32 >> 15) & 0xFFFu], 1);
  }
  __syncthreads();

  // Wave 0: find bucket B containing the 100th-largest kept score.
  if (tid < 64) {
    const int lane = tid;
    u32 p = 0;
    for (int t = 0; t < 64; ++t) p += hist[lane * 64 + t];
    u32 S = p;                               // inclusive suffix over chunks
    for (int off = 1; off < 64; off <<= 1) {
      u32 v = __shfl_down(S, off, 64);
      if (lane + off < 64) S += v;
    }
    u32 Sn = __shfl_down(S, 1, 64);
    if (lane == 63) Sn = 0;
    if (S >= 100u && Sn < 100u) { sC = lane; sNeed = 100u - Sn; }
    __builtin_amdgcn_wave_barrier();
    const int C = sC;
    const u32 need2 = sNeed;
    u32 T = hist[C * 64 + lane];             // inclusive suffix over bins
    for (int off = 1; off < 64; off <<= 1) {
      u32 v = __shfl_down(T, off, 64);
      if (lane + off < 64) T += v;
    }
    u32 Tn = __shfl_down(T, 1, 64);
    if (lane == 63) Tn = 0;
    if (T >= need2 && Tn < need2) sB = C * 64 + lane;
    __builtin_amdgcn_wave_barrier();
  }
  __syncthreads();
  const int B = sB;

  // Compact packed records with bucket >= B (typically ~110-200 entries).
  for (int e = tid; e < NREC; e += 256) {
    u64 pk = psarr[e];
    u32 k32 = (u32)(pk >> 32);
    if ((k32 >> 27) == 0x17u && (int)((k32 >> 15) & 0xFFFu) >= B) {
      int slot = atomicAdd(&selCount, 1);
      if (slot < SELCAP) sel[slot] = pk;
    }
  }
  __syncthreads();
  const int CB = min(selCount, SELCAP);

  // Rank-select the top 100 (packed keys unique; descending order == score
  // desc, then lowest flat index — matching lax.top_k).
  for (int r = tid; r < CB; r += 256) {
    u64 kr2 = sel[r];
    int rk = 0;
    for (int j = 0; j < CB; ++j) rk += (sel[j] > kr2) ? 1 : 0;
    if (rk < PERCLS) selSorted[rk] = kr2;
  }
  __syncthreads();

  if (tid < PERCLS) {
    u64 key = selSorted[tid];
    float* o = out + tid * 6;
    if (key != 0ULL) {
      int wcls = 79 - (int)((key >> 11) & 0x7Fu);
      u32 pi = 2047u - (u32)(key & 0x7FFu);
      int wc = wcls + 1;
      // Re-gather + re-clip the winner's box (bitwise-identical clip).
      float4 b = clip_box(*(const float4*)(boxes + (size_t)pi * (NCLS * 4) + wc * 4));
      o[0] = b.x; o[1] = b.y; o[2] = b.z; o[3] = b.w;
      o[4] = funflip((u32)(key >> 32));
      o[5] = (float)wc;
    } else {
      // only reachable if fewer than 100 detections survive globally
      o[0] = 0.f; o[1] = 0.f; o[2] = 0.f; o[3] = 0.f; o[4] = NEGINF; o[5] = 0.f;
    }
  }
}

extern "C" void kernel_launch(void* const* d_in, const int* in_sizes, int n_in,
                              void* d_out, int out_size, void* d_ws, size_t ws_size,
                              hipStream_t stream) {
  const float* boxes  = (const float*)d_in[0];   // [2048, 324]
  const float* scores = (const float*)d_in[1];   // [2048, 81]
  char* ws = (char*)d_ws;
  u32*  gdone = (u32*)ws;                        // [0,64)
  u32*  cnt   = (u32*)(ws + 64);                 // [64, 5184)
  u64*  keyws = (u64*)(ws + 5184);               // [5184, 126784)
  u64*  psarr = (u64*)(ws + 126784);             // [126784, 190784)
  float* out  = (float*)d_out;                   // [100, 6]

  hipMemsetAsync(ws, 0, 5184, stream);           // zero gdone + cnt
  scan_kernel<<<162, 256, 0, stream>>>((const float4*)scores, cnt, keyws);
  nms_topk_kernel<<<80, 256, 0, stream>>>(boxes, scores, cnt, keyws,
                                          psarr, gdone, out);
}

// Round 11
// 48.125 us; speedup vs baseline: 1.3562x; 1.3562x over previous
//
#include <hip/hip_runtime.h>
#include <stdint.h>

// Detection post-processor, two kernels, no memset node:
//  A (80 blocks, 1/class): strided per-class score scan into LDS (L2-served),
//    rank-sort + adjacency-mask greedy NMS + sarr/sidx emission.
//  B (1 block): global top-100 over sarr (histogram select) + output.
// N=2048 proposals, C=81 classes (class 0 dropped).
// Inputs:  d_in[0] = boxes  [2048, 324] f32, d_in[1] = scores [2048, 81] f32
// Output:  d_out = [100, 6] f32 (x1,y1,x2,y2,score,label)
// Workspace (48000 B used; every slot rewritten each call, no init needed):
//   [0]     f32 sarr[8000]   per-(class,rank) score (NEGINF pad)
//   [32000] u16 sidx[8000]   proposal index of each kept det

#define NPROP   2048
#define NCLS    81
#define SCORE_T 0.05f
#define NMS_T   0.5f
#define PERCLS  100
#define NREC    (80 * PERCLS)   // 8000
#define NEGINF  -1.0e9f
#define NBIN    4096
#define SELCAP  4096

typedef unsigned long long u64;
typedef unsigned int u32;
typedef unsigned short u16;

__device__ __forceinline__ u32 fflip(float f) {
  u32 u = __float_as_uint(f);
  return (u & 0x80000000u) ? ~u : (u | 0x80000000u);
}
__device__ __forceinline__ float funflip(u32 u) {
  u32 v = (u & 0x80000000u) ? (u ^ 0x80000000u) : ~u;
  return __uint_as_float(v);
}
__device__ __forceinline__ float4 clip_box(float4 r) {
  float4 b;
  b.x = fminf(fmaxf(r.x, 0.f), 1332.f);
  b.y = fminf(fmaxf(r.y, 0.f), 799.f);
  b.z = fminf(fmaxf(r.z, 0.f), 1332.f);
  b.w = fminf(fmaxf(r.w, 0.f), 799.f);
  return b;
}
// Reference IoU (exact expression; symmetric and f32-commutative).
__device__ __forceinline__ float iou_ref(float4 a, float aarea, float4 b,
                                         float barea) {
  float ix1 = fmaxf(a.x, b.x), iy1 = fmaxf(a.y, b.y);
  float ix2 = fminf(a.z, b.z), iy2 = fminf(a.w, b.w);
  float inter = fmaxf(ix2 - ix1, 0.f) * fmaxf(iy2 - iy1, 0.f);
  return inter / (aarea + barea - inter + 1e-9f);
}

// Sort key: [63:32] fflip(score), [31:0] ~proposal_idx. Descending order ==
// (score desc, idx asc) == the reference's stable argsort(-s_masked). Unique,
// so the LDS-atomic append order cannot affect the sorted result.

// ---- Kernel A: per-class scan + sort + mask-NMS + emission. ----
__global__ __launch_bounds__(256) void nms_kernel(
    const float* __restrict__ boxes, const float* __restrict__ scores,
    float* __restrict__ sarr, u16* __restrict__ sidx) {
  __shared__ u64 keysLds[NPROP];       // 16 KB
  __shared__ u64 sortedA[256];         //  2 KB (fast path M<=256)
  __shared__ float4 bxR[256];          //  4 KB rank-indexed boxes
  __shared__ float4 keptBx[PERCLS];
  __shared__ float keptArea[PERCLS];
  __shared__ float4 bxC[64];
  __shared__ int mcount, kkOut;

  const int tid = threadIdx.x;
  const int c = blockIdx.x + 1;                     // class 1..80
  const int cls = c - 1;

  if (tid == 0) mcount = 0;
  __syncthreads();

  // Strided per-class scan: 8 pipelined loads/thread. The 663 KB score
  // matrix is pulled through L2/LLC once and shared by all 80 blocks.
  for (int i = tid; i < NPROP; i += 256) {
    float s = scores[i * NCLS + c];
    if (s > SCORE_T) {
      int slot = atomicAdd(&mcount, 1);
      keysLds[slot] = ((u64)fflip(s) << 32) | (u32)(~(u32)i);
    }
  }
  __syncthreads();
  const int M = mcount;
  const bool fast = (M <= 256);

  if (fast) {
    // Rank sort (one barrier); box gather issued EARLY so it overlaps the
    // rank loop; thread places key+box directly at its own rank.
    if (tid < M) {
      u64 kr = keysLds[tid];
      u32 pi = (~(u32)kr) & (NPROP - 1);
      float4 raw = *(const float4*)(boxes + (size_t)pi * (NCLS * 4) + c * 4);
      int rk = 0;
      for (int j = 0; j < M; ++j) rk += (keysLds[j] > kr) ? 1 : 0;
      sortedA[rk] = kr;
      bxR[rk] = clip_box(raw);
    }
    __syncthreads();
  } else {
    // Slow fallback (correctness only): block bitonic over pow2 P.
    int P = 256; while (P < M) P <<= 1;
    for (int i = M + tid; i < P; i += 256) keysLds[i] = 0ULL;
    __syncthreads();
    for (int k = 2; k <= P; k <<= 1) {
      for (int j = k >> 1; j > 0; j >>= 1) {
        for (int i = tid; i < P; i += 256) {
          int ixj = i ^ j;
          if (ixj > i) {
            u64 a = keysLds[i], b = keysLds[ixj];
            if (((i & k) == 0) ? (a < b) : (a > b)) { keysLds[i] = b; keysLds[ixj] = a; }
          }
        }
        __syncthreads();
      }
    }
  }
  const u64* SK = fast ? sortedA : keysLds;

  float* sbase = sarr + cls * PERCLS;
  u16* ibase = sidx + cls * PERCLS;

  // ---- Greedy NMS, adjacency-mask form (wave 0 only). Semantics identical
  // to greedy: a candidate dies iff an earlier KEPT candidate has IoU>thresh.
  if (tid < 64) {
    const int lane = tid;
    int kkTot = 0;
    const int NC = (M + 63) >> 6;
    for (int q = 0; q < NC && kkTot < PERCLS; ++q) {
      const int cbase = q << 6;
      const int ccnt = min(64, M - cbase);
      u64 mykey = 0ULL;
      float4 b = make_float4(0.f, 0.f, 0.f, 0.f);
      int alive = 0;
      if (lane < ccnt) {
        mykey = SK[cbase + lane];
        if (fast) {
          b = bxR[cbase + lane];
        } else {
          u32 pi = ~(u32)mykey;
          b = clip_box(*(const float4*)(boxes + (size_t)pi * (NCLS * 4) + c * 4));
        }
        alive = 1;
      }
      bxC[lane] = b;                       // stage chunk boxes (wave-sync)
      const float barea = fmaxf(b.z - b.x, 0.f) * fmaxf(b.w - b.y, 0.f);
      __builtin_amdgcn_wave_barrier();

      // (0) cross-chunk: dead if any already-kept box overlaps me.
      for (int t = 0; t < kkTot; ++t) {
        float4 kb = keptBx[t];
        if (iou_ref(kb, keptArea[t], b, barea) > NMS_T) alive = 0;
      }

      // (a) intra-chunk suppression row: bits j > lane with IoU > thresh.
      u64 supRow = 0ULL;
      for (int j = 0; j < ccnt; ++j) {
        float4 ob = bxC[j];                // LDS broadcast
        float oarea = fmaxf(ob.z - ob.x, 0.f) * fmaxf(ob.w - ob.y, 0.f);
        bool hit = (j > lane) && (iou_ref(b, barea, ob, oarea) > NMS_T);
        supRow |= (u64)(hit ? 1u : 0u) << j;
      }
      const u32 rowLo = (u32)supRow, rowHi = (u32)(supRow >> 32);

      // (b) scalar propagation over alive candidates in rank order.
      u64 work = __ballot(alive != 0);
      u64 kept = 0ULL;
      while (work) {
        int i = (int)__builtin_ctzll(work);
        u32 rl = __builtin_amdgcn_readlane(rowLo, i);
        u32 rh = __builtin_amdgcn_readlane(rowHi, i);
        kept |= 1ull << i;
        work &= ~(((u64)rh << 32) | rl);
        work &= work - 1;                  // clear bit i
      }

      // cap at PERCLS kept per class (trim highest ranks; then we stop).
      int budget = PERCLS - kkTot;
      int over = (int)__popcll(kept) - budget;
      while (over-- > 0) kept &= ~(1ull << (63 - __builtin_clzll(kept)));

      // (c) parallel emission in rank order.
      if ((kept >> lane) & 1ull) {
        int rank = kkTot + (int)__popcll(kept & ((1ull << lane) - 1ull));
        sarr[cls * PERCLS + rank] = funflip((u32)(mykey >> 32));
        ibase[rank] = (u16)(~(u32)mykey);
        keptBx[rank] = b;
        keptArea[rank] = barea;
      }
      kkTot += (int)__popcll(kept);
      __builtin_amdgcn_wave_barrier();
    }
    if (lane == 0) kkOut = kkTot;
  }
  __syncthreads();

  // Pad remaining slots (every sarr/sidx slot is written every call).
  for (int slot = kkOut + tid; slot < PERCLS; slot += 256) {
    sbase[slot] = NEGINF;
    ibase[slot] = 0;
  }
}

// ---- Kernel B: global top-100 (1 block). Kernel boundary = ordering. ----
__global__ __launch_bounds__(256) void topk_kernel(
    const float* __restrict__ boxes, const float* __restrict__ sarr,
    const u16* __restrict__ sidx, float* __restrict__ out) {
  __shared__ u32 hist[NBIN];           // 16 KB
  __shared__ u64 sel[SELCAP];          // 32 KB
  __shared__ u64 selSorted[128];       //  1 KB
  __shared__ int selCount;
  __shared__ volatile int sC, sB;
  __shared__ volatile u32 sNeed;
  const int tid = threadIdx.x;

  for (int b = tid; b < NBIN; b += 256) hist[b] = 0;
  if (tid == 0) { selCount = 0; sC = 0; sNeed = 1; sB = 0; }
  if (tid < 128) selSorted[tid] = 0ULL;
  __syncthreads();

  // Histogram. Bucket = bits [26:15] of fflip(score): kept scores in
  // (0.05,1] share fflip's top 5 bits (0b10111) so bucket order == score
  // order; NEGINF pads fail the tag test and are skipped.
  const float4* s4p = (const float4*)sarr;
  for (int e4 = tid; e4 < NREC / 4; e4 += 256) {
    float4 s4 = s4p[e4];
    #pragma unroll
    for (int t = 0; t < 4; ++t) {
      float sv = (t == 0) ? s4.x : (t == 1) ? s4.y : (t == 2) ? s4.z : s4.w;
      u32 k32 = fflip(sv);
      if ((k32 >> 27) == 0x17u) atomicAdd(&hist[(k32 >> 15) & 0xFFFu], 1);
    }
  }
  __syncthreads();

  // Wave 0: find bucket B containing the 100th-largest kept score.
  if (tid < 64) {
    const int lane = tid;
    u32 p = 0;
    for (int t = 0; t < 64; ++t) p += hist[lane * 64 + t];
    u32 S = p;                               // inclusive suffix over chunks
    for (int off = 1; off < 64; off <<= 1) {
      u32 v = __shfl_down(S, off, 64);
      if (lane + off < 64) S += v;
    }
    u32 Sn = __shfl_down(S, 1, 64);
    if (lane == 63) Sn = 0;
    if (S >= 100u && Sn < 100u) { sC = lane; sNeed = 100u - Sn; }
    __builtin_amdgcn_wave_barrier();
    const int C = sC;
    const u32 need2 = sNeed;
    u32 T = hist[C * 64 + lane];             // inclusive suffix over bins
    for (int off = 1; off < 64; off <<= 1) {
      u32 v = __shfl_down(T, off, 64);
      if (lane + off < 64) T += v;
    }
    u32 Tn = __shfl_down(T, 1, 64);
    if (lane == 63) Tn = 0;
    if (T >= need2 && Tn < need2) sB = C * 64 + lane;
    __builtin_amdgcn_wave_barrier();
  }
  __syncthreads();
  const int B = sB;

  // Compact entries with bucket >= B (typically ~110-200).
  for (int e4 = tid; e4 < NREC / 4; e4 += 256) {
    float4 s4 = s4p[e4];
    #pragma unroll
    for (int t = 0; t < 4; ++t) {
      float sv = (t == 0) ? s4.x : (t == 1) ? s4.y : (t == 2) ? s4.z : s4.w;
      u32 k32 = fflip(sv);
      if ((k32 >> 27) == 0x17u && (int)((k32 >> 15) & 0xFFFu) >= B) {
        int slot = atomicAdd(&selCount, 1);
        int e = e4 * 4 + t;
        if (slot < SELCAP) sel[slot] = ((u64)k32 << 32) | (u32)(~(u32)e);
      }
    }
  }
  __syncthreads();
  const int CB = min(selCount, SELCAP);

  // Rank-select the top 100 (keys unique via ~e; tie order == lowest flat
  // index first, matching lax.top_k — (class, rank) lex order is preserved).
  for (int r = tid; r < CB; r += 256) {
    u64 kr2 = sel[r];
    int rk = 0;
    for (int j = 0; j < CB; ++j) rk += (sel[j] > kr2) ? 1 : 0;
    if (rk < PERCLS) selSorted[rk] = kr2;
  }
  __syncthreads();

  if (tid < PERCLS) {
    u64 key = selSorted[tid];
    float* o = out + tid * 6;
    if (key != 0ULL) {
      u32 e = ~(u32)key;
      int wc = (int)(e / PERCLS) + 1;        // class label from entry index
      u32 pi = sidx[e];
      // Re-gather + re-clip the winner's box (bitwise-identical clip).
      float4 b = clip_box(*(const float4*)(boxes + (size_t)pi * (NCLS * 4) + wc * 4));
      o[0] = b.x; o[1] = b.y; o[2] = b.z; o[3] = b.w;
      o[4] = funflip((u32)(key >> 32));
      o[5] = (float)wc;
    } else {
      // only reachable if fewer than 100 detections survive globally
      o[0] = 0.f; o[1] = 0.f; o[2] = 0.f; o[3] = 0.f; o[4] = NEGINF; o[5] = 0.f;
    }
  }
}

extern "C" void kernel_launch(void* const* d_in, const int* in_sizes, int n_in,
                              void* d_out, int out_size, void* d_ws, size_t ws_size,
                              hipStream_t stream) {
  const float* boxes  = (const float*)d_in[0];   // [2048, 324]
  const float* scores = (const float*)d_in[1];   // [2048, 81]
  char* ws = (char*)d_ws;
  float* sarr = (float*)ws;                      // [0, 32000)
  u16*   sidx = (u16*)(ws + 32000);              // [32000, 48000)
  float* out  = (float*)d_out;                   // [100, 6]

  nms_kernel<<<80, 256, 0, stream>>>(boxes, scores, sarr, sidx);
  topk_kernel<<<1, 256, 0, stream>>>(boxes, sarr, sidx, out);
}